// Round 1
// baseline (207.118 us; speedup 1.0000x reference)
//
#include <hip/hip_runtime.h>

#define VOCAB 67
#define EMB 50
#define NUM_LAYERS 8

// Kernel 1: build the 67x67 logit lookup table.
// One block per vocab id v; the whole forward pass for that token.
__global__ void build_table(const float* __restrict__ emb,
                            const float* __restrict__ kappa,
                            const float* __restrict__ phi,
                            const float* __restrict__ W_out,
                            const float* __restrict__ b_out,
                            float* __restrict__ table) {
    __shared__ float ar[EMB], ai[EMB], nr[EMB], ni[EMB], inten[EMB];
    const int v = blockIdx.x;
    const int t = threadIdx.x;

    if (t < EMB) { ar[t] = emb[v * EMB + t]; ai[t] = 0.f; }
    __syncthreads();

    for (int l = 0; l < NUM_LAYERS; ++l) {
        if (t < EMB) {
            const float* k = kappa + l * EMB * EMB;
            const float* p = phi   + l * EMB * EMB;
            float sr = 0.f, si = 0.f;
            // nr[f] = sum_e ar[e]*k[e][f] - ai[e]*p[e][f]  (f = t: coalesced)
            #pragma unroll 10
            for (int e = 0; e < EMB; ++e) {
                float a_r = ar[e], a_i = ai[e];
                float kk = k[e * EMB + t];
                float pp = p[e * EMB + t];
                sr = fmaf(a_r, kk, sr);
                sr = fmaf(-a_i, pp, sr);
                si = fmaf(a_r, pp, si);
                si = fmaf(a_i, kk, si);
            }
            nr[t] = sr; ni[t] = si;
        }
        __syncthreads();
        if (t < EMB) { ar[t] = nr[t]; ai[t] = ni[t]; }
        __syncthreads();
    }

    if (t < EMB) inten[t] = ar[t] * ar[t] + ai[t] * ai[t];
    __syncthreads();

    for (int j = t; j < VOCAB; j += blockDim.x) {
        float s = b_out[j];
        #pragma unroll 10
        for (int e = 0; e < EMB; ++e)
            s = fmaf(inten[e], W_out[e * VOCAB + j], s);
        table[v * VOCAB + j] = s;
    }
}

// Kernel 2: out[row, :] = table[seq[row], :], written as float4 chunks.
// out_size (= 64*8192*67 = 35,127,296) is divisible by 4 and the base is
// 16B-aligned, so every chunk is a clean dwordx4 store. A chunk crosses a
// row boundary at most once (4 < 67).
__global__ void gather_logits(const int* __restrict__ seq,
                              const float* __restrict__ table,
                              float4* __restrict__ out,
                              unsigned int n4, unsigned int nrows) {
    __shared__ float lut[VOCAB * VOCAB];
    for (int i = threadIdx.x; i < VOCAB * VOCAB; i += blockDim.x)
        lut[i] = table[i];
    __syncthreads();

    const unsigned int stride = gridDim.x * blockDim.x;
    for (unsigned int c = blockIdx.x * blockDim.x + threadIdx.x; c < n4; c += stride) {
        unsigned int e = c * 4u;
        unsigned int row = e / VOCAB;            // magic-multiply, 32-bit
        int col = (int)(e - row * VOCAB);
        int base = seq[row] * VOCAB;
        float vals[4];
        #pragma unroll
        for (int q = 0; q < 4; ++q) {
            vals[q] = lut[base + col];
            if (++col == VOCAB) {
                col = 0;
                ++row;
                base = (row < nrows) ? seq[row] * VOCAB : 0;
            }
        }
        out[c] = make_float4(vals[0], vals[1], vals[2], vals[3]);
    }
}

extern "C" void kernel_launch(void* const* d_in, const int* in_sizes, int n_in,
                              void* d_out, int out_size, void* d_ws, size_t ws_size,
                              hipStream_t stream) {
    const int*   seq    = (const int*)  d_in[0];
    const float* emb    = (const float*)d_in[1];
    const float* kappa  = (const float*)d_in[2];
    const float* phi    = (const float*)d_in[3];
    const float* W_out  = (const float*)d_in[4];
    const float* b_out  = (const float*)d_in[5];
    float* out   = (float*)d_out;
    float* table = (float*)d_ws;   // 67*67*4 = 17,956 bytes

    build_table<<<dim3(VOCAB), dim3(64), 0, stream>>>(emb, kappa, phi, W_out, b_out, table);

    const unsigned int nrows = (unsigned int)in_sizes[0];      // 64*8192
    const unsigned int n4    = (unsigned int)(out_size / 4);   // divisible
    gather_logits<<<dim3(4096), dim3(256), 0, stream>>>(seq, table, (float4*)out, n4, nrows);
}

// Round 2
// 194.777 us; speedup vs baseline: 1.0634x; 1.0634x over previous
//
#include <hip/hip_runtime.h>

#define VOCAB 67
#define EMB 50
#define NUM_LAYERS 8

// Kernel 1: build the 67x67 logit lookup table.
// One block per vocab id v; the whole forward pass for that token.
// Total compute ~10.7 MFLOP — latency-bound, ~10 us.
__global__ void build_table(const float* __restrict__ emb,
                            const float* __restrict__ kappa,
                            const float* __restrict__ phi,
                            const float* __restrict__ W_out,
                            const float* __restrict__ b_out,
                            float* __restrict__ table) {
    __shared__ float ar[EMB], ai[EMB], nr[EMB], ni[EMB], inten[EMB];
    const int v = blockIdx.x;
    const int t = threadIdx.x;

    if (t < EMB) { ar[t] = emb[v * EMB + t]; ai[t] = 0.f; }
    __syncthreads();

    for (int l = 0; l < NUM_LAYERS; ++l) {
        if (t < EMB) {
            const float* k = kappa + l * EMB * EMB;
            const float* p = phi   + l * EMB * EMB;
            float sr = 0.f, si = 0.f;
            // nr[f] = sum_e ar[e]*k[e][f] - ai[e]*p[e][f]  (f = t: coalesced)
            #pragma unroll 10
            for (int e = 0; e < EMB; ++e) {
                float a_r = ar[e], a_i = ai[e];
                float kk = k[e * EMB + t];
                float pp = p[e * EMB + t];
                sr = fmaf(a_r, kk, sr);
                sr = fmaf(-a_i, pp, sr);
                si = fmaf(a_r, pp, si);
                si = fmaf(a_i, kk, si);
            }
            nr[t] = sr; ni[t] = si;
        }
        __syncthreads();
        if (t < EMB) { ar[t] = nr[t]; ai[t] = ni[t]; }
        __syncthreads();
    }

    if (t < EMB) inten[t] = ar[t] * ar[t] + ai[t] * ai[t];
    __syncthreads();

    for (int j = t; j < VOCAB; j += blockDim.x) {
        float s = b_out[j];
        #pragma unroll 10
        for (int e = 0; e < EMB; ++e)
            s = fmaf(inten[e], W_out[e * VOCAB + j], s);
        table[v * VOCAB + j] = s;
    }
}

// Kernel 2: out[row, :] = table[seq[row], :], written as float4 chunks.
// Branchless: a 4-float chunk crosses at most one row boundary (4 < 67),
// so both candidate row bases are fetched up front and each element is a
// cndmask-selected LDS read. Store is a clean global_store_dwordx4.
__global__ void gather_logits(const int* __restrict__ seq,
                              const float* __restrict__ table,
                              float4* __restrict__ out,
                              unsigned int n4, unsigned int nrows) {
    __shared__ float lut[VOCAB * VOCAB];
    for (int i = threadIdx.x; i < VOCAB * VOCAB; i += blockDim.x)
        lut[i] = table[i];
    __syncthreads();

    const unsigned int stride = gridDim.x * blockDim.x;
    for (unsigned int c = blockIdx.x * blockDim.x + threadIdx.x; c < n4; c += stride) {
        const unsigned int e = c * 4u;
        const unsigned int r0 = e / VOCAB;          // magic-multiply div
        const unsigned int col0 = e - r0 * VOCAB;
        unsigned int r1 = r0 + 1u;
        if (r1 >= nrows) r1 = nrows - 1u;           // wrap never actually uses OOB row
        const int b0 = seq[r0] * VOCAB;
        const int b1 = seq[r1] * VOCAB;

        const unsigned int c1 = col0 + 1u, c2 = col0 + 2u, c3 = col0 + 3u;
        float4 v;
        v.x = lut[b0 + (int)col0];
        v.y = lut[c1 >= VOCAB ? b1 + (int)(c1 - VOCAB) : b0 + (int)c1];
        v.z = lut[c2 >= VOCAB ? b1 + (int)(c2 - VOCAB) : b0 + (int)c2];
        v.w = lut[c3 >= VOCAB ? b1 + (int)(c3 - VOCAB) : b0 + (int)c3];
        out[c] = v;
    }
}

extern "C" void kernel_launch(void* const* d_in, const int* in_sizes, int n_in,
                              void* d_out, int out_size, void* d_ws, size_t ws_size,
                              hipStream_t stream) {
    const int*   seq    = (const int*)  d_in[0];
    const float* emb    = (const float*)d_in[1];
    const float* kappa  = (const float*)d_in[2];
    const float* phi    = (const float*)d_in[3];
    const float* W_out  = (const float*)d_in[4];
    const float* b_out  = (const float*)d_in[5];
    float* out   = (float*)d_out;
    float* table = (float*)d_ws;   // 67*67*4 = 17,956 bytes

    build_table<<<dim3(VOCAB), dim3(64), 0, stream>>>(emb, kappa, phi, W_out, b_out, table);

    const unsigned int nrows = (unsigned int)in_sizes[0];      // 64*8192 rows
    const unsigned int n4    = (unsigned int)(out_size / 4);   // exactly divisible
    gather_logits<<<dim3(4096), dim3(256), 0, stream>>>(seq, table, (float4*)out, n4, nrows);
}